// Round 13
// baseline (370.540 us; speedup 1.0000x reference)
//
#include <hip/hip_runtime.h>
#include <hip/hip_bf16.h>
#include <stdint.h>

#define ENC_DIM 2048
#define DEC_DIM 512
#define ATT_DIM 512
#define BATCH   256
#define PIX     196
#define M_TOTAL (BATCH*PIX)   // 50176
#define NT      (ENC_DIM/32)  // 64 K-tiles of BK=32

typedef unsigned short u16;
typedef __attribute__((ext_vector_type(8))) short  bf16x8;
typedef __attribute__((ext_vector_type(4))) float  f32x4;

// ---------- helpers ----------
__device__ __forceinline__ void gll16(const void* g, void* l) {
    __builtin_amdgcn_global_load_lds(
        (const __attribute__((address_space(1))) unsigned int*)g,
        (__attribute__((address_space(3))) unsigned int*)l,
        16, 0, 0);
}

union Pack8 {
    uint4 u;
    __hip_bfloat16 h[8];
};

union Pack4 {
    uint2 u;
    __hip_bfloat16 h[4];
};

__device__ __forceinline__ uint4 cvt8(float4 a, float4 b) {
    Pack8 p;
    p.h[0] = __float2bfloat16(a.x); p.h[1] = __float2bfloat16(a.y);
    p.h[2] = __float2bfloat16(a.z); p.h[3] = __float2bfloat16(a.w);
    p.h[4] = __float2bfloat16(b.x); p.h[5] = __float2bfloat16(b.y);
    p.h[6] = __float2bfloat16(b.z); p.h[7] = __float2bfloat16(b.w);
    return p.u;
}

__device__ __forceinline__ uint2 cvt4(float4 a) {
    Pack4 p;
    p.h[0] = __float2bfloat16(a.x); p.h[1] = __float2bfloat16(a.y);
    p.h[2] = __float2bfloat16(a.z); p.h[3] = __float2bfloat16(a.w);
    return p.u;
}

// ---------- kernel 1: W_enc fp32 -> bf16 ----------
__global__ void k_convert(const float* __restrict__ W, u16* __restrict__ Wb) {
    int idx = blockIdx.x * 256 + threadIdx.x;
    const float4* s = (const float4*)W + (size_t)idx * 2;
    ((uint4*)Wb)[idx] = cvt8(s[0], s[1]);
}

// ---------- kernel 2: att2[b,a] = dec[b,:].W_dec[a,:] + b_enc[a] + b_dec[a] ----------
__global__ void k_att2(const float* __restrict__ dec, const float* __restrict__ Wd,
                       const float* __restrict__ b_enc, const float* __restrict__ b_dec,
                       float* __restrict__ att2f) {
    int b = blockIdx.x;
    int t = threadIdx.x;
    __shared__ float dec_s[DEC_DIM];
    ((float2*)dec_s)[t] = ((const float2*)(dec + (size_t)b * DEC_DIM))[t];
    __syncthreads();
    #pragma unroll
    for (int rep = 0; rep < 2; ++rep) {
        int a = t + rep * 256;
        const float4* w = (const float4*)(Wd + (size_t)a * DEC_DIM);
        float acc = 0.f;
        #pragma unroll 4
        for (int e = 0; e < DEC_DIM / 4; ++e) {
            float4 wv = w[e];
            float4 dv = ((const float4*)dec_s)[e];
            acc += wv.x * dv.x + wv.y * dv.y + wv.z * dv.z + wv.w * dv.w;
        }
        att2f[(size_t)b * ATT_DIM + a] = acc + b_enc[a] + b_dec[a];
    }
}

// ---------- kernel 3: fused GEMM, BM=64 BN=512 BK=32, 72KB LDS -> 2 blocks/CU ----------
// 512 threads = 8 waves (2M x 4N), per-wave 32x128, acc[2][8] (64 VGPR).
// LDS 72KB: A dbuf 2x4KB (reg-staged fp32->bf16), B dbuf 2x32KB (gll16).
// R9/R11 schedule: one barrier/tile, counted vmcnt. Per tile/wave: 4 gll16
// (older) + 1 A float4 (newer) -> VMC(1) completes gll16 + prior A, keeps
// newest A. 2 blocks/CU: co-resident block hides barrier/vmcnt stalls.
// Swizzle (64B rows, 4x16B slots): physical slot = logical ^ ((row>>1)&3),
// applied write-side for A (reg-staged) and source-side for B (rule #21).

#define FENCE  asm volatile("" ::: "memory")
#define LGKM0  asm volatile("s_waitcnt lgkmcnt(0)" ::: "memory")
#define VMC(N) asm volatile("s_waitcnt vmcnt(" #N ")" ::: "memory")
#define SBARF  do { FENCE; __builtin_amdgcn_s_barrier(); FENCE; } while (0)

// 1 fp32x4 load for A-tile KT: thread t covers row t>>3, cols (t&7)*4..+3
#define ISSUE_A(KT, F) do { F = *(const float4*)(a_src + (size_t)(KT) * 32); } while (0)

// cvt + 1 swizzled ds_write_b64 into As[Q]
#define WRITE_A(Q, F) do { *(uint2*)(&As[Q][aw_off]) = cvt4(F); } while (0)

// 4 gll16 staging the 512x32 B-tile KT into Bs[Q] (pre-swizzled source)
#define STAGE_B(KT, Q) do { const u16* _b = b_src + (size_t)(KT) * 32;                 \
    _Pragma("unroll") for (int s = 0; s < 4; ++s)                                      \
        gll16(_b + (size_t)s * 128 * ENC_DIM, &Bs[Q][(s * 128 + wave * 16) * 32]); } while (0)

#define COMPUTE(P) do {                                                                \
    bf16x8 af[2], bf[8];                                                               \
    _Pragma("unroll") for (int m = 0; m < 2; ++m)                                      \
        af[m] = *(const bf16x8*)(&As[P][a_row_off + m * 512 + axo]);                   \
    _Pragma("unroll") for (int n = 0; n < 8; ++n)                                      \
        bf[n] = *(const bf16x8*)(&Bs[P][b_row_off + n * 512 + axo]);                   \
    __builtin_amdgcn_s_setprio(1);                                                     \
    _Pragma("unroll") for (int m = 0; m < 2; ++m)                                      \
        _Pragma("unroll") for (int n = 0; n < 8; ++n)                                  \
            acc[m][n] = __builtin_amdgcn_mfma_f32_16x16x32_bf16(af[m], bf[n], acc[m][n], 0, 0, 0); \
    __builtin_amdgcn_s_setprio(0); } while (0)

__global__ void __launch_bounds__(512, 4)
k_gemm(const float* __restrict__ enc, const u16* __restrict__ Wb,
       const float* __restrict__ att2f, const float* __restrict__ Wfull,
       float* __restrict__ att_part) {
    const int mb = blockIdx.x;                 // 784 blocks, BN covers all of N
    const int t  = threadIdx.x;
    const int lane = t & 63, wave = t >> 6;
    const int wm = wave >> 2, wn = wave & 3;   // 2M x 4N wave grid
    const int fr = lane & 15, fq = lane >> 4;

    __shared__ u16 As[2][64 * 32];   // 2 x 4 KB
    __shared__ u16 Bs[2][512 * 32];  // 2 x 32 KB   (total 72 KB -> 2 blocks/CU)

    f32x4 acc[2][8];
    #pragma unroll
    for (int m = 0; m < 2; ++m)
        #pragma unroll
        for (int n = 0; n < 8; ++n)
            acc[m][n] = (f32x4){0.f, 0.f, 0.f, 0.f};

    // A staging: thread t covers row t>>3 (0..63), cols (t&7)*4..+3 (128B/row group)
    const int arow = t >> 3;
    const float* a_src = enc + (size_t)(mb * 64 + arow) * ENC_DIM + (t & 7) * 4;
    // write: logical 16B-slot (t&7)>>1, half t&1; physical slot ^= (arow>>1)&3
    const int aw_off = arow * 32 + ((((t & 7) >> 1) ^ ((arow >> 1) & 3)) * 8) + (t & 1) * 4;

    // B staging via gll16: gll16 s covers rows s*128 + wave*16 + (l>>2), slot l&3;
    // source octet pre-swizzled: c = (l&3) ^ ((l>>3)&3)  [= (row>>1)&3 per-lane]
    const u16* b_src = Wb + (size_t)(wave * 16 + (lane >> 2)) * ENC_DIM
                          + (((lane & 3) ^ ((lane >> 3) & 3)) * 8);

    // fragment reads: physical slot = fq ^ ((fr>>1)&3)  (2-way residual, free)
    const int axo = (fq ^ ((fr >> 1) & 3)) * 8;
    const int a_row_off = (wm * 32 + fr) * 32;
    const int b_row_off = (wn * 128 + fr) * 32;

    float4 pA, pB;   // 2 regs carry a 3-deep A pipeline (rule #20: static names)

    // ---- prologue ----
    ISSUE_A(0, pA); FENCE;
    STAGE_B(0, 0);          // gll16 x4 (newer than A(0))
    WRITE_A(0, pA);         // implicit wait vmcnt(4) -> A(0) ready
    FENCE; ISSUE_A(1, pB);
    FENCE; ISSUE_A(2, pA);
    VMC(2);                 // completes gll16(0)x4; keeps A(1),A(2)
    LGKM0;
    SBARF;                  // Bs[0], As[0] visible

    // ---- main loop: tiles 0..59, one barrier per tile, issue A(kt+3) ----
    for (int kt = 0; kt < NT - 4; kt += 2) {
        // even tile kt (P=0): consume A(kt+1)=pB, issue A(kt+3)->pB
        WRITE_A(1, pB);                // implicit vmcnt(1): waits A(kt+1), keeps A(kt+2)
        STAGE_B(kt + 1, 1); FENCE;     // 4 gll16
        ISSUE_A(kt + 3, pB);           // newest
        COMPUTE(0);
        VMC(1);                        // completes A(kt+2)+gll16(kt+1); keeps A(kt+3)
        LGKM0;
        SBARF;
        // odd tile kt+1 (P=1): consume A(kt+2)=pA, issue A(kt+4)->pA
        WRITE_A(0, pA);
        STAGE_B(kt + 2, 0); FENCE;
        ISSUE_A(kt + 4, pA);
        COMPUTE(1);
        VMC(1);
        LGKM0;
        SBARF;
    }

    // ---- tile 60 (P=0): consume A(61)=pB, issue A(63)->pB ----
    {
        WRITE_A(1, pB);
        STAGE_B(61, 1); FENCE;
        ISSUE_A(63, pB);
        COMPUTE(0);
        VMC(1);                        // completes A(62)+gll16(61); keeps A(63)
        LGKM0;
        SBARF;
    }
    // ---- tile 61 (P=1): consume A(62)=pA (already complete) ----
    {
        WRITE_A(0, pA);
        STAGE_B(62, 0);
        COMPUTE(1);
        VMC(0);                        // gll16(62) newer than A(63): full drain
        LGKM0;
        SBARF;
    }
    // ---- tile 62 (P=0): consume A(63)=pB ----
    {
        WRITE_A(1, pB);
        STAGE_B(63, 1);
        COMPUTE(0);
        VMC(0);
        LGKM0;
        SBARF;
    }
    // ---- tile 63 (P=1): pure compute ----
    COMPUTE(1);

    // ---- epilogue: +att2, relu, dot W_full, 16-lane reduce ----
    // C/D layout: col = lane&15, row = (lane>>4)*4 + reg  [m89/m91]
    const int row_base = mb * 64 + wm * 32 + fq * 4;
    const int col_base = wn * 128 + fr;
    float wf[8];
    #pragma unroll
    for (int n = 0; n < 8; ++n) wf[n] = Wfull[col_base + n * 16];

    #pragma unroll
    for (int m = 0; m < 2; ++m) {
        #pragma unroll
        for (int r = 0; r < 4; ++r) {
            const int grow = row_base + m * 16 + r;
            const int bidx = grow / PIX;
            const float* a2 = att2f + (size_t)bidx * ATT_DIM;
            float ssum = 0.f;
            #pragma unroll
            for (int n = 0; n < 8; ++n) {
                float v = acc[m][n][r] + a2[col_base + n * 16];
                v = fmaxf(v, 0.f);
                ssum += v * wf[n];
            }
            #pragma unroll
            for (int off = 1; off < 16; off <<= 1)
                ssum += __shfl_xor(ssum, off, 64);
            if (fr == 0)
                att_part[(size_t)wn * M_TOTAL + grow] = ssum;
        }
    }
}

// ---------- kernel 4: per-b softmax over 196 + alpha-weighted enc reduction ----------
__global__ void k_soft(const float* __restrict__ att_part, const float* __restrict__ enc,
                       float* __restrict__ out) {
    const int b  = blockIdx.x >> 1;
    const int ec = blockIdx.x & 1;   // e-chunk of 1024
    const int t  = threadIdx.x;
    __shared__ float red[256];
    __shared__ float alpha_s[PIX];

    float myatt = -1e30f;
    if (t < PIX) {
        float s = 0.f;
        #pragma unroll
        for (int j = 0; j < 4; ++j) s += att_part[(size_t)j * M_TOTAL + b * PIX + t];
        myatt = s;
    }
    red[t] = myatt;
    __syncthreads();
    for (int o = 128; o > 0; o >>= 1) {
        if (t < o) red[t] = fmaxf(red[t], red[t + o]);
        __syncthreads();
    }
    const float mx = red[0];
    __syncthreads();
    float e = 0.f;
    if (t < PIX) e = __expf(myatt - mx);
    red[t] = e;
    __syncthreads();
    for (int o = 128; o > 0; o >>= 1) {
        if (t < o) red[t] += red[t + o];
        __syncthreads();
    }
    const float inv = 1.f / red[0];
    if (t < PIX) {
        float al = e * inv;
        alpha_s[t] = al;
        if (ec == 0) out[(size_t)BATCH * ENC_DIM + b * PIX + t] = al;   // alpha output
    }
    __syncthreads();

    float4 acc = {0.f, 0.f, 0.f, 0.f};
    const float* ebase = enc + (size_t)b * PIX * ENC_DIM + ec * 1024 + t * 4;
    #pragma unroll 4
    for (int p = 0; p < PIX; ++p) {
        float4 x = *(const float4*)(ebase + (size_t)p * ENC_DIM);
        float a = alpha_s[p];
        acc.x += a * x.x; acc.y += a * x.y; acc.z += a * x.z; acc.w += a * x.w;
    }
    *(float4*)(out + (size_t)b * ENC_DIM + ec * 1024 + t * 4) = acc;
}

extern "C" void kernel_launch(void* const* d_in, const int* in_sizes, int n_in,
                              void* d_out, int out_size, void* d_ws, size_t ws_size,
                              hipStream_t stream) {
    const float* enc    = (const float*)d_in[0];
    const float* dec    = (const float*)d_in[1];
    const float* W_enc  = (const float*)d_in[2];
    const float* b_enc  = (const float*)d_in[3];
    const float* W_dec  = (const float*)d_in[4];
    const float* b_dec  = (const float*)d_in[5];
    const float* W_full = (const float*)d_in[6];
    // d_in[7] (b_full) unused: softmax is shift-invariant, att is not an output.

    char* ws = (char*)d_ws;
    u16*   Wb    = (u16*)ws;                                    // 2 MB bf16 W_enc
    float* att2f = (float*)(ws + 2 * 1024 * 1024);              // 512 KB
    float* att_p = (float*)(ws + 2 * 1024 * 1024 + 512 * 1024); // 4 * 50176 * 4 B

    hipLaunchKernelGGL(k_convert, dim3(512), dim3(256), 0, stream, W_enc, Wb);
    hipLaunchKernelGGL(k_att2,    dim3(256), dim3(256), 0, stream, dec, W_dec, b_enc, b_dec, att2f);
    hipLaunchKernelGGL(k_gemm,    dim3(784), dim3(512), 0, stream, enc, Wb, att2f, W_full, att_p);
    hipLaunchKernelGGL(k_soft,    dim3(512), dim3(256), 0, stream, att_p, enc, (float*)d_out);
}

// Round 15
// 357.842 us; speedup vs baseline: 1.0355x; 1.0355x over previous
//
#include <hip/hip_runtime.h>
#include <hip/hip_bf16.h>
#include <stdint.h>

#define ENC_DIM 2048
#define DEC_DIM 512
#define ATT_DIM 512
#define BATCH   256
#define PIX     196
#define M_TOTAL (BATCH*PIX)   // 50176
#define NT      (ENC_DIM/64)  // 32 K-tiles of BK=64 (16 groups of 2)

typedef unsigned short u16;
typedef __attribute__((ext_vector_type(8))) short  bf16x8;
typedef __attribute__((ext_vector_type(4))) float  f32x4;

// ---------- helpers ----------
__device__ __forceinline__ void gll16(const void* g, void* l) {
    __builtin_amdgcn_global_load_lds(
        (const __attribute__((address_space(1))) unsigned int*)g,
        (__attribute__((address_space(3))) unsigned int*)l,
        16, 0, 0);
}

union Pack8 {
    uint4 u;
    __hip_bfloat16 h[8];
};

union Pack4 {
    uint2 u;
    __hip_bfloat16 h[4];
};

__device__ __forceinline__ uint4 cvt8(float4 a, float4 b) {
    Pack8 p;
    p.h[0] = __float2bfloat16(a.x); p.h[1] = __float2bfloat16(a.y);
    p.h[2] = __float2bfloat16(a.z); p.h[3] = __float2bfloat16(a.w);
    p.h[4] = __float2bfloat16(b.x); p.h[5] = __float2bfloat16(b.y);
    p.h[6] = __float2bfloat16(b.z); p.h[7] = __float2bfloat16(b.w);
    return p.u;
}

__device__ __forceinline__ uint2 cvt4(float4 a) {
    Pack4 p;
    p.h[0] = __float2bfloat16(a.x); p.h[1] = __float2bfloat16(a.y);
    p.h[2] = __float2bfloat16(a.z); p.h[3] = __float2bfloat16(a.w);
    return p.u;
}

// ---------- kernel 1: W_enc fp32 -> bf16 ----------
__global__ void k_convert(const float* __restrict__ W, u16* __restrict__ Wb) {
    int idx = blockIdx.x * 256 + threadIdx.x;
    const float4* s = (const float4*)W + (size_t)idx * 2;
    ((uint4*)Wb)[idx] = cvt8(s[0], s[1]);
}

// ---------- kernel 2: att2[b,a] = dec[b,:].W_dec[a,:] + b_enc[a] + b_dec[a] ----------
__global__ void k_att2(const float* __restrict__ dec, const float* __restrict__ Wd,
                       const float* __restrict__ b_enc, const float* __restrict__ b_dec,
                       float* __restrict__ att2f) {
    int b = blockIdx.x;
    int t = threadIdx.x;
    __shared__ float dec_s[DEC_DIM];
    ((float2*)dec_s)[t] = ((const float2*)(dec + (size_t)b * DEC_DIM))[t];
    __syncthreads();
    #pragma unroll
    for (int rep = 0; rep < 2; ++rep) {
        int a = t + rep * 256;
        const float4* w = (const float4*)(Wd + (size_t)a * DEC_DIM);
        float acc = 0.f;
        #pragma unroll 4
        for (int e = 0; e < DEC_DIM / 4; ++e) {
            float4 wv = w[e];
            float4 dv = ((const float4*)dec_s)[e];
            acc += wv.x * dv.x + wv.y * dv.y + wv.z * dv.z + wv.w * dv.w;
        }
        att2f[(size_t)b * ATT_DIM + a] = acc + b_enc[a] + b_dec[a];
    }
}

// ---------- kernel 3: fused GEMM, R11 shell + coarse-granule A bursts ----------
// BM=128, BN=512, BK=64. 512 threads = 8 waves (2M x 4N). LDS 160KB exact.
// A-fetch: ONE 8x dwordx4 burst per 2-tile group (128 cols): each load instr
// covers 128B contiguous per row (vs 32B in R11) -> 4x coarser DRAM granule.
// Theory: the ~128 cy/Kcol plateau is DRAM row-thrash from fine-grained
// streams; coarser granule raises achieved HBM BW. All else = R11 (263us).
// R14 crash root-caused: unguarded ISSUE_A(16) read OOB; this rewrite has
// provable bounds (max burst idx 15 -> col<=2047; max stage tile 31).

#define FENCE  asm volatile("" ::: "memory")
#define LGKM0  asm volatile("s_waitcnt lgkmcnt(0)" ::: "memory")
#define VMC(N) asm volatile("s_waitcnt vmcnt(" #N ")" ::: "memory")
#define SBARF  do { FENCE; __builtin_amdgcn_s_barrier(); FENCE; } while (0)

// A burst for group G (tiles {2G,2G+1}, cols [G*128, G*128+128)):
// thread t covers rows arow, arow+64; F[k] = 16B at col k*32+(t&7)*4 of row
// arow (8 lanes x 16B = 128B contiguous per instr); F[4+k] same for arow+64.
#define ISSUE_A(G, F) do { const float* _p = a_src + (size_t)(G) * 128;                \
    F[0] = *(const float4*)(_p);                                                       \
    F[1] = *(const float4*)(_p + 32);                                                  \
    F[2] = *(const float4*)(_p + 64);                                                  \
    F[3] = *(const float4*)(_p + 96);                                                  \
    F[4] = *(const float4*)(_p + (size_t)64 * ENC_DIM);                                \
    F[5] = *(const float4*)(_p + (size_t)64 * ENC_DIM + 32);                           \
    F[6] = *(const float4*)(_p + (size_t)64 * ENC_DIM + 64);                           \
    F[7] = *(const float4*)(_p + (size_t)64 * ENC_DIM + 96); } while (0)

// write one tile (group half TL) from burst regs: 4x swizzled ds_write_b64.
// local element k_loc*32 + h8*4 -> logical slot k_loc*4+h2, half h1;
// physical slot = logical ^ (arow&7)  [same mapping as R11, verified]
#define WRITE_A(Q, F, TL) do {                                                         \
    *(uint2*)(&As[Q][awA])        = cvt4(F[2*(TL)]);                                   \
    *(uint2*)(&As[Q][awB])        = cvt4(F[2*(TL) + 1]);                               \
    *(uint2*)(&As[Q][awA + 4096]) = cvt4(F[4 + 2*(TL)]);                               \
    *(uint2*)(&As[Q][awB + 4096]) = cvt4(F[5 + 2*(TL)]); } while (0)

// 8 gll16 staging the 512x64 B-tile KT into Bs[Q]
#define STAGE_B(KT, Q) do { const u16* _b = b_src + (size_t)(KT) * 64;                 \
    _Pragma("unroll") for (int s = 0; s < 8; ++s)                                      \
        gll16(_b + (size_t)s * 64 * ENC_DIM, &Bs[Q][s * 4096 + b_dst]); } while (0)

#define COMPUTE(P) do {                                                                \
    _Pragma("unroll") for (int ks = 0; ks < 2; ++ks) {                                 \
        const int _axo = ks ? axo1 : axo0;                                             \
        bf16x8 af[4], bf[8];                                                           \
        _Pragma("unroll") for (int m = 0; m < 4; ++m)                                  \
            af[m] = *(const bf16x8*)(&As[P][a_row_off + m * 1024 + _axo]);             \
        _Pragma("unroll") for (int n = 0; n < 8; ++n)                                  \
            bf[n] = *(const bf16x8*)(&Bs[P][b_row_off + n * 1024 + _axo]);             \
        __builtin_amdgcn_s_setprio(1);                                                 \
        _Pragma("unroll") for (int m = 0; m < 4; ++m)                                  \
            _Pragma("unroll") for (int n = 0; n < 8; ++n)                              \
                acc[m][n] = __builtin_amdgcn_mfma_f32_16x16x32_bf16(af[m], bf[n], acc[m][n], 0, 0, 0); \
        __builtin_amdgcn_s_setprio(0);                                                 \
    } } while (0)

__global__ void __launch_bounds__(512, 1)
k_gemm(const float* __restrict__ enc, const u16* __restrict__ Wb,
       const float* __restrict__ att2f, const float* __restrict__ Wfull,
       float* __restrict__ att_part) {
    const int mb = blockIdx.x;                 // 392 blocks, BN covers all of N
    const int t  = threadIdx.x;
    const int lane = t & 63, wave = t >> 6;
    const int wm = wave >> 2, wn = wave & 3;   // 2M x 4N wave grid
    const int fr = lane & 15, fq = lane >> 4;

    __shared__ u16 As[2][128 * 64];  // 2 x 16 KB
    __shared__ u16 Bs[2][512 * 64];  // 2 x 64 KB  (total LDS 160 KB exact)

    f32x4 acc[4][8];
    #pragma unroll
    for (int m = 0; m < 4; ++m)
        #pragma unroll
        for (int n = 0; n < 8; ++n)
            acc[m][n] = (f32x4){0.f, 0.f, 0.f, 0.f};

    // A burst addressing: rows arow, arow+64; 16B piece at col k*32 + h8*4
    const int arow = t >> 3;         // 0..63
    const int h8   = t & 7;
    const float* a_src = enc + (size_t)(mb * 128 + arow) * ENC_DIM + h8 * 4;
    const int r7a = arow & 7, h2 = h8 >> 1, h1 = h8 & 1;
    const int awA = arow * 64 + ((h2    ) ^ r7a) * 8 + h1 * 4;   // local piece 0
    const int awB = arow * 64 + ((4 + h2) ^ r7a) * 8 + h1 * 4;   // local piece 1

    // B staging via gll16: pre-swizzled source (rule #21), linear dest
    const int brl = lane >> 3, bslot = lane & 7;
    const u16* b_src = Wb + (size_t)(wave * 8 + brl) * ENC_DIM + ((bslot ^ brl)) * 8;
    const int b_dst = (wave * 8) * 64;

    // fragment reads: slot = ((ks<<2)|fq) ^ (fr&7)
    const int r7 = fr & 7;
    const int axo0 = ((fq    ) ^ r7) * 8;
    const int axo1 = ((fq | 4) ^ r7) * 8;
    const int a_row_off = (wm * 64 + fr) * 64;
    const int b_row_off = (wn * 128 + fr) * 64;

    float4 fE[8], fO[8];   // burst regs, parity per group (rule #20)

    // ---- prologue: Bs[0]<-B(0) (oldest), burst group0 (newest), As[0]<-tile0 ----
    STAGE_B(0, 0);
    ISSUE_A(0, fE); FENCE;
    WRITE_A(0, fE, 0);     // implicit wait F0,F1,F4,F5 -> also retires gll16(0)
    LGKM0;
    SBARF;                 // Bs[0], As[0] visible (F6,F7 may remain in flight)

    // ---- main loop: group pairs (g even: fE, g+1: fO); 16 groups, 32 tiles ----
    for (int g = 0; g < 16; g += 2) {
        // ======== group g (burst fE) ========
        // phase A: compute tile 2g; write tile 2g+1; stage B(2g+1); issue burst g+1
        WRITE_A(1, fE, 1);               // F2,F3,F6,F7 (implicit wait; near-complete)
        STAGE_B(2 * g + 1, 1); FENCE;    // 8 gll16 (oldest in window)
        ISSUE_A(g + 1, fO);              // burst g+1 <= 15: in bounds
        COMPUTE(0);
        VMC(8); LGKM0; SBARF;            // retire gll16(2g+1); keep burst fO
        // phase B: compute tile 2g+1; write tile 2g+2; stage B(2g+2)
        WRITE_A(0, fO, 0);               // pacing point: fO had 1 compute window
        STAGE_B(2 * g + 2, 0);           // 2g+2 <= 30: in bounds
        COMPUTE(1);
        VMC(0); LGKM0; SBARF;            // retire gll16(2g+2) + fO tail

        // ======== group g+1 (burst fO) ========
        // phase A: compute tile 2g+2; write tile 2g+3; stage B(2g+3); issue burst g+2
        WRITE_A(1, fO, 1);
        STAGE_B(2 * g + 3, 1); FENCE;    // 2g+3 <= 31: in bounds
        if (g + 2 < 16) ISSUE_A(g + 2, fE);   // GUARDED (R14 crash fix)
        COMPUTE(0);
        if (g + 2 < 16) { VMC(8); } else { VMC(0); }
        LGKM0; SBARF;
        // phase B: compute tile 2g+3; write tile 2g+4; stage B(2g+4)
        if (g + 2 < 16) {
            WRITE_A(0, fE, 0);
            STAGE_B(2 * g + 4, 0);       // 2g+4 <= 30 when guard passes
        }
        COMPUTE(1);
        if (g + 2 < 16) { VMC(0); LGKM0; }
        SBARF;
    }

    // ---- epilogue: +att2, relu, dot W_full, 16-lane reduce ----
    // C/D layout: col = lane&15, row = (lane>>4)*4 + reg  [m89/m91]
    const int row_base = mb * 128 + wm * 64 + fq * 4;
    const int col_base = wn * 128 + fr;
    float wf[8];
    #pragma unroll
    for (int n = 0; n < 8; ++n) wf[n] = Wfull[col_base + n * 16];

    #pragma unroll
    for (int m = 0; m < 4; ++m) {
        #pragma unroll
        for (int r = 0; r < 4; ++r) {
            const int grow = row_base + m * 16 + r;
            const int bidx = grow / PIX;
            const float* a2 = att2f + (size_t)bidx * ATT_DIM;
            float ssum = 0.f;
            #pragma unroll
            for (int n = 0; n < 8; ++n) {
                float v = acc[m][n][r] + a2[col_base + n * 16];
                v = fmaxf(v, 0.f);
                ssum += v * wf[n];
            }
            #pragma unroll
            for (int off = 1; off < 16; off <<= 1)
                ssum += __shfl_xor(ssum, off, 64);
            if (fr == 0)
                att_part[(size_t)wn * M_TOTAL + grow] = ssum;
        }
    }
}

// ---------- kernel 4: per-b softmax over 196 + alpha-weighted enc reduction ----------
__global__ void k_soft(const float* __restrict__ att_part, const float* __restrict__ enc,
                       float* __restrict__ out) {
    const int b  = blockIdx.x >> 1;
    const int ec = blockIdx.x & 1;   // e-chunk of 1024
    const int t  = threadIdx.x;
    __shared__ float red[256];
    __shared__ float alpha_s[PIX];

    float myatt = -1e30f;
    if (t < PIX) {
        float s = 0.f;
        #pragma unroll
        for (int j = 0; j < 4; ++j) s += att_part[(size_t)j * M_TOTAL + b * PIX + t];
        myatt = s;
    }
    red[t] = myatt;
    __syncthreads();
    for (int o = 128; o > 0; o >>= 1) {
        if (t < o) red[t] = fmaxf(red[t], red[t + o]);
        __syncthreads();
    }
    const float mx = red[0];
    __syncthreads();
    float e = 0.f;
    if (t < PIX) e = __expf(myatt - mx);
    red[t] = e;
    __syncthreads();
    for (int o = 128; o > 0; o >>= 1) {
        if (t < o) red[t] += red[t + o];
        __syncthreads();
    }
    const float inv = 1.f / red[0];
    if (t < PIX) {
        float al = e * inv;
        alpha_s[t] = al;
        if (ec == 0) out[(size_t)BATCH * ENC_DIM + b * PIX + t] = al;   // alpha output
    }
    __syncthreads();

    float4 acc = {0.f, 0.f, 0.f, 0.f};
    const float* ebase = enc + (size_t)b * PIX * ENC_DIM + ec * 1024 + t * 4;
    #pragma unroll 4
    for (int p = 0; p < PIX; ++p) {
        float4 x = *(const float4*)(ebase + (size_t)p * ENC_DIM);
        float a = alpha_s[p];
        acc.x += a * x.x; acc.y += a * x.y; acc.z += a * x.z; acc.w += a * x.w;
    }
    *(float4*)(out + (size_t)b * ENC_DIM + ec * 1024 + t * 4) = acc;
}

extern "C" void kernel_launch(void* const* d_in, const int* in_sizes, int n_in,
                              void* d_out, int out_size, void* d_ws, size_t ws_size,
                              hipStream_t stream) {
    const float* enc    = (const float*)d_in[0];
    const float* dec    = (const float*)d_in[1];
    const float* W_enc  = (const float*)d_in[2];
    const float* b_enc  = (const float*)d_in[3];
    const float* W_dec  = (const float*)d_in[4];
    const float* b_dec  = (const float*)d_in[5];
    const float* W_full = (const float*)d_in[6];
    // d_in[7] (b_full) unused: softmax is shift-invariant, att is not an output.

    char* ws = (char*)d_ws;
    u16*   Wb    = (u16*)ws;                                    // 2 MB bf16 W_enc
    float* att2f = (float*)(ws + 2 * 1024 * 1024);              // 512 KB
    float* att_p = (float*)(ws + 2 * 1024 * 1024 + 512 * 1024); // 4 * 50176 * 4 B

    hipLaunchKernelGGL(k_convert, dim3(512), dim3(256), 0, stream, W_enc, Wb);
    hipLaunchKernelGGL(k_att2,    dim3(256), dim3(256), 0, stream, dec, W_dec, b_enc, b_dec, att2f);
    hipLaunchKernelGGL(k_gemm,    dim3(392), dim3(512), 0, stream, enc, Wb, att2f, W_full, att_p);
    hipLaunchKernelGGL(k_soft,    dim3(512), dim3(256), 0, stream, att_p, enc, (float*)d_out);
}

// Round 16
// 261.540 us; speedup vs baseline: 1.4168x; 1.3682x over previous
//
#include <hip/hip_runtime.h>
#include <hip/hip_bf16.h>
#include <stdint.h>

#define ENC_DIM 2048
#define DEC_DIM 512
#define ATT_DIM 512
#define BATCH   256
#define PIX     196
#define M_TOTAL (BATCH*PIX)   // 50176
#define NT      (ENC_DIM/64)  // 32 K-tiles

typedef unsigned short u16;
typedef __attribute__((ext_vector_type(8))) short  bf16x8;
typedef __attribute__((ext_vector_type(4))) float  f32x4;

// ---------- helpers ----------
__device__ __forceinline__ void gll16(const void* g, void* l) {
    __builtin_amdgcn_global_load_lds(
        (const __attribute__((address_space(1))) unsigned int*)g,
        (__attribute__((address_space(3))) unsigned int*)l,
        16, 0, 0);
}

union Pack8 {
    uint4 u;
    __hip_bfloat16 h[8];
};

__device__ __forceinline__ uint4 cvt8(float4 a, float4 b) {
    Pack8 p;
    p.h[0] = __float2bfloat16(a.x); p.h[1] = __float2bfloat16(a.y);
    p.h[2] = __float2bfloat16(a.z); p.h[3] = __float2bfloat16(a.w);
    p.h[4] = __float2bfloat16(b.x); p.h[5] = __float2bfloat16(b.y);
    p.h[6] = __float2bfloat16(b.z); p.h[7] = __float2bfloat16(b.w);
    return p.u;
}

// ---------- kernel 1: W_enc fp32 -> bf16 ----------
__global__ void k_convert(const float* __restrict__ W, u16* __restrict__ Wb) {
    int idx = blockIdx.x * 256 + threadIdx.x;
    const float4* s = (const float4*)W + (size_t)idx * 2;
    ((uint4*)Wb)[idx] = cvt8(s[0], s[1]);
}

// ---------- kernel 2: att2[b,a] = dec[b,:].W_dec[a,:] + b_enc[a] + b_dec[a] ----------
__global__ void k_att2(const float* __restrict__ dec, const float* __restrict__ Wd,
                       const float* __restrict__ b_enc, const float* __restrict__ b_dec,
                       float* __restrict__ att2f) {
    int b = blockIdx.x;
    int t = threadIdx.x;
    __shared__ float dec_s[DEC_DIM];
    ((float2*)dec_s)[t] = ((const float2*)(dec + (size_t)b * DEC_DIM))[t];
    __syncthreads();
    #pragma unroll
    for (int rep = 0; rep < 2; ++rep) {
        int a = t + rep * 256;
        const float4* w = (const float4*)(Wd + (size_t)a * DEC_DIM);
        float acc = 0.f;
        #pragma unroll 4
        for (int e = 0; e < DEC_DIM / 4; ++e) {
            float4 wv = w[e];
            float4 dv = ((const float4*)dec_s)[e];
            acc += wv.x * dv.x + wv.y * dv.y + wv.z * dv.z + wv.w * dv.w;
        }
        att2f[(size_t)b * ATT_DIM + a] = acc + b_enc[a] + b_dec[a];
    }
}

// ---------- kernel 3: fused GEMM, BN=512, BM=128, FULL double-buffer ----------
// Best verified structure (R9, 259.9us total): 512 threads = 8 waves
// (2M x 4N), per-wave 64x128. LDS 160KB exact:
//   A dbuf 2x16KB (reg-staged fp32->bf16, swizzled write),
//   B dbuf 2x64KB (gll16, pre-swizzled source; Wb is L2-resident).
// ONE barrier per K-tile: staging for kt+1 issued BEFORE COMPUTE(kt) so the
// gll16 flight lands under the MFMA phase; VMC(4) drains the 8 gll16
// (oldest in FIFO) and keeps the 4 A-prefetch loads (newest) in flight.
// setprio removed this round (m190: harmful on lockstep GEMM).

#define FENCE  asm volatile("" ::: "memory")
#define LGKM0  asm volatile("s_waitcnt lgkmcnt(0)" ::: "memory")
#define VMC(N) asm volatile("s_waitcnt vmcnt(" #N ")" ::: "memory")
#define SBARF  do { FENCE; __builtin_amdgcn_s_barrier(); FENCE; } while (0)

// 4 fp32x4 loads for A-tile KT: thread t covers rows {0,64}+(t>>3), octet t&7
#define ISSUE_A(KT, F) do { const float* _p = a_src + (size_t)(KT) * 64;               \
    F[0] = *(const float4*)(_p);                                                       \
    F[1] = *(const float4*)(_p + 4);                                                   \
    F[2] = *(const float4*)(_p + (size_t)64 * ENC_DIM);                                \
    F[3] = *(const float4*)(_p + (size_t)64 * ENC_DIM + 4); } while (0)

// cvt + 2 swizzled ds_write_b128 into As[Q] (implicit wait on F's loads here;
// those loads had a full tile in flight -> near-free)
#define WRITE_A(Q, F) do {                                                             \
    *(uint4*)(&As[Q][aw_off])        = cvt8(F[0], F[1]);                               \
    *(uint4*)(&As[Q][aw_off + 4096]) = cvt8(F[2], F[3]); } while (0)

// 8 gll16 staging the 512x64 B-tile KT into Bs[Q]
#define STAGE_B(KT, Q) do { const u16* _b = b_src + (size_t)(KT) * 64;                 \
    _Pragma("unroll") for (int s = 0; s < 8; ++s)                                      \
        gll16(_b + (size_t)s * 64 * ENC_DIM, &Bs[Q][s * 4096 + b_dst]); } while (0)

#define COMPUTE(P) do {                                                                \
    _Pragma("unroll") for (int ks = 0; ks < 2; ++ks) {                                 \
        const int _axo = ks ? axo1 : axo0;                                             \
        bf16x8 af[4], bf[8];                                                           \
        _Pragma("unroll") for (int m = 0; m < 4; ++m)                                  \
            af[m] = *(const bf16x8*)(&As[P][a_row_off + m * 1024 + _axo]);             \
        _Pragma("unroll") for (int n = 0; n < 8; ++n)                                  \
            bf[n] = *(const bf16x8*)(&Bs[P][b_row_off + n * 1024 + _axo]);             \
        _Pragma("unroll") for (int m = 0; m < 4; ++m)                                  \
            _Pragma("unroll") for (int n = 0; n < 8; ++n)                              \
                acc[m][n] = __builtin_amdgcn_mfma_f32_16x16x32_bf16(af[m], bf[n], acc[m][n], 0, 0, 0); \
    } } while (0)

__global__ void __launch_bounds__(512, 1)
k_gemm(const float* __restrict__ enc, const u16* __restrict__ Wb,
       const float* __restrict__ att2f, const float* __restrict__ Wfull,
       float* __restrict__ att_part) {
    const int mb = blockIdx.x;                 // 392 blocks, BN covers all of N
    const int t  = threadIdx.x;
    const int lane = t & 63, wave = t >> 6;
    const int wm = wave >> 2, wn = wave & 3;   // 2M x 4N wave grid
    const int fr = lane & 15, fq = lane >> 4;

    __shared__ u16 As[2][128 * 64];  // 2 x 16 KB
    __shared__ u16 Bs[2][512 * 64];  // 2 x 64 KB  (total LDS 160 KB exact)

    f32x4 acc[4][8];
    #pragma unroll
    for (int m = 0; m < 4; ++m)
        #pragma unroll
        for (int n = 0; n < 8; ++n)
            acc[m][n] = (f32x4){0.f, 0.f, 0.f, 0.f};

    // A staging: thread t covers rows {0,64} + (t>>3), k-octet t&7
    const int arow  = t >> 3;        // 0..63
    const int aslot = t & 7;
    const float* a_src = enc + (size_t)(mb * 128 + arow) * ENC_DIM + aslot * 8;
    const int aw_off = arow * 64 + ((aslot ^ (arow & 7))) * 8;   // +4096 for row+64

    // B staging via gll16: lane covers row s*64 + wave*8 + (l>>3), slot l&7;
    // source octet pre-swizzled (rule #21), dest linear (HW adds lane*16B)
    const int brl = lane >> 3, bslot = lane & 7;
    const u16* b_src = Wb + (size_t)(wave * 8 + brl) * ENC_DIM + ((bslot ^ brl)) * 8;
    const int b_dst = (wave * 8) * 64;

    // fragment reads: A row = wm*64 + m*16 + fr; B row = wn*128 + n*16 + fr;
    // slot = ((ks<<2)|fq) ^ (fr&7)
    const int r7 = fr & 7;
    const int axo0 = ((fq    ) ^ r7) * 8;
    const int axo1 = ((fq | 4) ^ r7) * 8;
    const int a_row_off = (wm * 64 + fr) * 64;
    const int b_row_off = (wn * 128 + fr) * 64;

    float4 eE[4], eO[4];   // 2-deep A-reg pipeline, parity-named (rule #20)

    // ---- prologue (gll16 before next A-issue: FIFO order) ----
    ISSUE_A(0, eE); FENCE;
    STAGE_B(0, 0);
    WRITE_A(0, eE);        // implicit wait on A(0) regs (gll16 newer, stay)
    FENCE; ISSUE_A(1, eO);
    VMC(4);                // completes 8 gll16(0); keeps A(1) x4 in flight
    LGKM0;
    SBARF;                 // Bs[0]=B(0), As[0]=A(0) visible

    // ---- main loop: tiles 0..29, one barrier per tile ----
    for (int kt = 0; kt < NT - 2; kt += 2) {
        // even tile kt (P=0): stage kt+1 -> buf1 BEFORE compute
        WRITE_A(1, eO);                // A(kt+1) -> As[1] (regs had a full tile)
        STAGE_B(kt + 1, 1); FENCE;     // gll16 first (oldest in FIFO)
        ISSUE_A(kt + 2, eE);           // A prefetch second (newest)
        COMPUTE(0);                    // gll16 flight hides under MFMA
        VMC(4);                        // drains gll16(kt+1); keeps A(kt+2)
        LGKM0;
        SBARF;
        // odd tile kt+1 (P=1): stage kt+2 -> buf0
        WRITE_A(0, eE);
        STAGE_B(kt + 2, 0); FENCE;
        ISSUE_A(kt + 3, eO);
        COMPUTE(1);
        VMC(4);
        LGKM0;
        SBARF;
    }

    // ---- tile 30 (P=0): stage tile 31 -> buf1, no more A issues ----
    {
        WRITE_A(1, eO);                // A(31) -> As[1]
        STAGE_B(31, 1);
        COMPUTE(0);
        VMC(0);                        // full drain
        LGKM0;
        SBARF;
    }
    // ---- tile 31 (P=1): pure compute ----
    COMPUTE(1);

    // ---- epilogue: +att2, relu, dot W_full, 16-lane reduce ----
    // C/D layout: col = lane&15, row = (lane>>4)*4 + reg  [m89/m91]
    const int row_base = mb * 128 + wm * 64 + fq * 4;
    const int col_base = wn * 128 + fr;
    float wf[8];
    #pragma unroll
    for (int n = 0; n < 8; ++n) wf[n] = Wfull[col_base + n * 16];

    #pragma unroll
    for (int m = 0; m < 4; ++m) {
        #pragma unroll
        for (int r = 0; r < 4; ++r) {
            const int grow = row_base + m * 16 + r;
            const int bidx = grow / PIX;
            const float* a2 = att2f + (size_t)bidx * ATT_DIM;
            float ssum = 0.f;
            #pragma unroll
            for (int n = 0; n < 8; ++n) {
                float v = acc[m][n][r] + a2[col_base + n * 16];
                v = fmaxf(v, 0.f);
                ssum += v * wf[n];
            }
            #pragma unroll
            for (int off = 1; off < 16; off <<= 1)
                ssum += __shfl_xor(ssum, off, 64);
            if (fr == 0)
                att_part[(size_t)wn * M_TOTAL + grow] = ssum;
        }
    }
}

// ---------- kernel 4: per-b softmax over 196 + alpha-weighted enc reduction ----------
__global__ void k_soft(const float* __restrict__ att_part, const float* __restrict__ enc,
                       float* __restrict__ out) {
    const int b  = blockIdx.x >> 1;
    const int ec = blockIdx.x & 1;   // e-chunk of 1024
    const int t  = threadIdx.x;
    __shared__ float red[256];
    __shared__ float alpha_s[PIX];

    float myatt = -1e30f;
    if (t < PIX) {
        float s = 0.f;
        #pragma unroll
        for (int j = 0; j < 4; ++j) s += att_part[(size_t)j * M_TOTAL + b * PIX + t];
        myatt = s;
    }
    red[t] = myatt;
    __syncthreads();
    for (int o = 128; o > 0; o >>= 1) {
        if (t < o) red[t] = fmaxf(red[t], red[t + o]);
        __syncthreads();
    }
    const float mx = red[0];
    __syncthreads();
    float e = 0.f;
    if (t < PIX) e = __expf(myatt - mx);
    red[t] = e;
    __syncthreads();
    for (int o = 128; o > 0; o >>= 1) {
        if (t < o) red[t] += red[t + o];
        __syncthreads();
    }
    const float inv = 1.f / red[0];
    if (t < PIX) {
        float al = e * inv;
        alpha_s[t] = al;
        if (ec == 0) out[(size_t)BATCH * ENC_DIM + b * PIX + t] = al;   // alpha output
    }
    __syncthreads();

    float4 acc = {0.f, 0.f, 0.f, 0.f};
    const float* ebase = enc + (size_t)b * PIX * ENC_DIM + ec * 1024 + t * 4;
    #pragma unroll 4
    for (int p = 0; p < PIX; ++p) {
        float4 x = *(const float4*)(ebase + (size_t)p * ENC_DIM);
        float a = alpha_s[p];
        acc.x += a * x.x; acc.y += a * x.y; acc.z += a * x.z; acc.w += a * x.w;
    }
    *(float4*)(out + (size_t)b * ENC_DIM + ec * 1024 + t * 4) = acc;
}

extern "C" void kernel_launch(void* const* d_in, const int* in_sizes, int n_in,
                              void* d_out, int out_size, void* d_ws, size_t ws_size,
                              hipStream_t stream) {
    const float* enc    = (const float*)d_in[0];
    const float* dec    = (const float*)d_in[1];
    const float* W_enc  = (const float*)d_in[2];
    const float* b_enc  = (const float*)d_in[3];
    const float* W_dec  = (const float*)d_in[4];
    const float* b_dec  = (const float*)d_in[5];
    const float* W_full = (const float*)d_in[6];
    // d_in[7] (b_full) unused: softmax is shift-invariant, att is not an output.

    char* ws = (char*)d_ws;
    u16*   Wb    = (u16*)ws;                                    // 2 MB bf16 W_enc
    float* att2f = (float*)(ws + 2 * 1024 * 1024);              // 512 KB
    float* att_p = (float*)(ws + 2 * 1024 * 1024 + 512 * 1024); // 4 * 50176 * 4 B

    hipLaunchKernelGGL(k_convert, dim3(512), dim3(256), 0, stream, W_enc, Wb);
    hipLaunchKernelGGL(k_att2,    dim3(256), dim3(256), 0, stream, dec, W_dec, b_enc, b_dec, att2f);
    hipLaunchKernelGGL(k_gemm,    dim3(392), dim3(512), 0, stream, enc, Wb, att2f, W_full, att_p);
    hipLaunchKernelGGL(k_soft,    dim3(512), dim3(256), 0, stream, att_p, enc, (float*)d_out);
}